// Round 1
// baseline (405.827 us; speedup 1.0000x reference)
//
#include <hip/hip_runtime.h>

#define NB   32   // batch
#define CIN_ 128
#define NW   8    // N filters
#define KK   9
#define DCMAX 16  // CIN/8
#define LL   32

// out[b, n*32+j, y, w] = sum_{dc,ky,kx} x[b,(4j-dc)&127,(y-ky)&31,(w-kx)&31] * wgt[n,dc,ky,kx]
__global__ __launch_bounds__(256, 2) void fconv_kernel(
    const float* __restrict__ x,
    const float* __restrict__ wgt,
    float* __restrict__ out)
{
    // weights reordered: sw[((dc*9 + kx)*9 + ky)*8 + n]
    __shared__ float sw[DCMAX * KK * KK * NW];

    const int tid = threadIdx.x;
    for (int idx = tid; idx < NW * DCMAX * KK * KK; idx += 256) {
        int n  = idx / (DCMAX * KK * KK);
        int r  = idx - n * (DCMAX * KK * KK);
        int dc = r / (KK * KK);
        int r2 = r - dc * (KK * KK);
        int ky = r2 / KK;
        int kx = r2 - ky * KK;
        sw[((dc * KK + kx) * KK + ky) * NW + n] = wgt[idx];
    }
    __syncthreads();

    const int bid = blockIdx.x;          // 2048 blocks = 32 b * 32 j * 2 yhalf
    const int b   = bid >> 6;
    const int j   = (bid >> 1) & 31;
    const int yh  = bid & 1;

    const int xw     = tid & 31;         // output w
    const int yg     = tid >> 5;         // 0..7
    const int y_base = yh * 16 + yg * 2; // each thread: 2 consecutive y rows

    // precomputed row byte-offsets for the sliding window: y = (y_base - 8 + i) mod 32
    int rows[10];
    #pragma unroll
    for (int i = 0; i < 10; ++i)
        rows[i] = ((y_base + 24 + i) & 31) << 5;   // *32 floats per row

    float acc[NW][2];
    #pragma unroll
    for (int n = 0; n < NW; ++n) { acc[n][0] = 0.f; acc[n][1] = 0.f; }

    const int c0 = 4 * j;

    #pragma unroll 1
    for (int dc = 0; dc < DCMAX; ++dc) {
        const int c_src = (c0 - dc) & (CIN_ - 1);
        const float* bx = x + (((size_t)b * CIN_ + c_src) << 10);
        #pragma unroll 1
        for (int kx = 0; kx < KK; ++kx) {
            const int x_col = (xw - kx) & 31;
            float win[10];
            #pragma unroll
            for (int i = 0; i < 10; ++i)
                win[i] = bx[rows[i] + x_col];
            const float4* wp = (const float4*)&sw[((dc * KK + kx) * KK) * NW];
            #pragma unroll
            for (int ky = 0; ky < KK; ++ky) {
                float4 wA = wp[2 * ky];       // n = 0..3
                float4 wB = wp[2 * ky + 1];   // n = 4..7
                float x0 = win[8 - ky];       // t = 0 : y = y_base - ky
                float x1 = win[9 - ky];       // t = 1 : y = y_base + 1 - ky
                acc[0][0] += x0 * wA.x; acc[0][1] += x1 * wA.x;
                acc[1][0] += x0 * wA.y; acc[1][1] += x1 * wA.y;
                acc[2][0] += x0 * wA.z; acc[2][1] += x1 * wA.z;
                acc[3][0] += x0 * wA.w; acc[3][1] += x1 * wA.w;
                acc[4][0] += x0 * wB.x; acc[4][1] += x1 * wB.x;
                acc[5][0] += x0 * wB.y; acc[5][1] += x1 * wB.y;
                acc[6][0] += x0 * wB.z; acc[6][1] += x1 * wB.z;
                acc[7][0] += x0 * wB.w; acc[7][1] += x1 * wB.w;
            }
        }
    }

    #pragma unroll
    for (int n = 0; n < NW; ++n) {
        float* op = out + ((((size_t)b * 256) + n * 32 + j) << 10) + (y_base << 5) + xw;
        op[0]  = acc[n][0];
        op[32] = acc[n][1];
    }
}

extern "C" void kernel_launch(void* const* d_in, const int* in_sizes, int n_in,
                              void* d_out, int out_size, void* d_ws, size_t ws_size,
                              hipStream_t stream) {
    const float* x   = (const float*)d_in[0];
    const float* w   = (const float*)d_in[1];
    float*       out = (float*)d_out;
    fconv_kernel<<<2048, 256, 0, stream>>>(x, w, out);
}

// Round 2
// 114.676 us; speedup vs baseline: 3.5389x; 3.5389x over previous
//
#include <hip/hip_runtime.h>

typedef __attribute__((ext_vector_type(4))) float  f32x4;
typedef __attribute__((ext_vector_type(8))) short  s16x8;

#define KK 9

__device__ inline unsigned short f2bf(float f) {
    union { float f; unsigned int u; } v; v.f = f;
    unsigned int u = v.u + 0x7FFFu + ((v.u >> 16) & 1u);   // RNE
    return (unsigned short)(u >> 16);
}

// ---------------------------------------------------------------------------
// prep_w: pack weights into B-fragment layout (bf16) in d_ws.
// Bg element index = ((chunk*4 + g)*16 + n)*8 + e
//   k = chunk*32 + g*8 + e ; pair p = k>>4 ; c' = k&15 ; dc = 15-c'
//   value = wgt[n, dc, ky=p/9, kx=p%9]  (0 if n>=8 or p>=81)
// ---------------------------------------------------------------------------
__global__ void prep_w(const float* __restrict__ wgt, unsigned short* __restrict__ Bg) {
    int idx = blockIdx.x * 256 + threadIdx.x;
    if (idx >= 41 * 4 * 16 * 8) return;
    int e = idx & 7;
    int n = (idx >> 3) & 15;
    int g = (idx >> 7) & 3;
    int c = idx >> 9;
    int k  = c * 32 + g * 8 + e;
    int p  = k >> 4;
    int cp = k & 15;
    float val = 0.f;
    if (n < 8 && p < 81) {
        int ky = p / 9;
        int kx = p - ky * 9;
        int dc = 15 - cp;
        val = wgt[((n * 16 + dc) * KK + ky) * KK + kx];
    }
    Bg[idx] = f2bf(val);
}

// ---------------------------------------------------------------------------
// Main MFMA kernel: one block per (b, j). M=1024 spatial, N=16 (8 used),
// K = 41 chunks x 32 (= (ky,kx) pairs x 16 channels, padded).
// ---------------------------------------------------------------------------
__global__ __launch_bounds__(256) void fconv_mfma(
    const float* __restrict__ x,
    const unsigned short* __restrict__ Bg,
    float* __restrict__ out)
{
    __shared__ unsigned short xs[16384];   // 32 KB: [half][spatial 1024][8 ch] bf16
    char* smb = (char*)xs;

    const int tid = threadIdx.x;
    const int b   = blockIdx.x >> 5;
    const int j   = blockIdx.x & 31;

    // ---- stage x tile: 16 channels (4j-15 .. 4j), bf16, channel-contiguous ----
    const float* xb = x + ((size_t)b << 17);   // b * 128*1024
    int choff[16];
    #pragma unroll
    for (int i = 0; i < 16; ++i)
        choff[i] = ((4 * j - 15 + i) & 127) << 10;   // uniform -> SGPR

    #pragma unroll
    for (int i = 0; i < 4; ++i) {
        int cell = i * 256 + tid;                    // spatial index y*32+w
        #pragma unroll
        for (int h = 0; h < 2; ++h) {
            union { unsigned short u16[8]; uint4 v; } pk;
            #pragma unroll
            for (int e = 0; e < 8; ++e)
                pk.u16[e] = f2bf(xb[choff[h * 8 + e] + cell]);
            *(uint4*)(smb + h * 16384 + cell * 16) = pk.v;
        }
    }
    __syncthreads();

    // ---- per-lane decomposition ----
    const int lane = tid & 63;
    const int wave = tid >> 6;        // 4 waves
    const int r    = lane & 15;       // A row (w offset) / B col (n)
    const int g    = lane >> 4;       // k-group 0..3
    const int half = g & 1;           // channel half
    const int pi   = g >> 1;          // which (ky,kx) pair within chunk
    const int y0   = wave * 8;        // 8 y rows per wave

    f32x4 acc[8][2];
    #pragma unroll
    for (int dy = 0; dy < 8; ++dy) { acc[dy][0] = (f32x4)0.f; acc[dy][1] = (f32x4)0.f; }

    // per-lane B pointer: byte offset = chunk*1024 + (g*16+r)*16
    const char* bptr = (const char*)Bg + ((g * 16 + r) << 4);
    s16x8 bfrag = *(const s16x8*)(bptr);

    #pragma unroll 1
    for (int c = 0; c < 41; ++c) {
        int p  = 2 * c + pi;
        int ky = p / 9;               // compiler magic-mul
        int kx = p - ky * 9;
        int wr = (r - kx) & 31;
        int yb = (y0 - ky) & 31;
        int abase = (half << 14) + (wr << 4);

        int cn = (c < 40) ? c + 1 : 40;
        s16x8 bnext = *(const s16x8*)(bptr + (cn << 10));

        #pragma unroll
        for (int dy = 0; dy < 8; ++dy) {
            int yy = (yb + dy) & 31;
            int ra = abase + (yy << 9);
            s16x8 a0 = *(const s16x8*)(smb + ra);
            s16x8 a1 = *(const s16x8*)(smb + (ra ^ 256));
            acc[dy][0] = __builtin_amdgcn_mfma_f32_16x16x32_bf16(a0, bfrag, acc[dy][0], 0, 0, 0);
            acc[dy][1] = __builtin_amdgcn_mfma_f32_16x16x32_bf16(a1, bfrag, acc[dy][1], 0, 0, 0);
        }
        bfrag = bnext;
    }

    // ---- epilogue: lane holds D[row = g*4+i][col = r] ; n = r (<8), w = h*16+g*4+i ----
    if (r < 8) {
        float* ob = out + (((size_t)(b * 256 + r * 32 + j)) << 10) + (g << 2);
        #pragma unroll
        for (int dy = 0; dy < 8; ++dy) {
            #pragma unroll
            for (int h = 0; h < 2; ++h) {
                *(float4*)(ob + (y0 + dy) * 32 + h * 16) = *(float4*)&acc[dy][h];
            }
        }
    }
}

// ---------------------------------------------------------------------------
// Fallback (round-1 fp32 VALU kernel) if workspace is too small.
// ---------------------------------------------------------------------------
__global__ __launch_bounds__(256, 2) void fconv_fallback(
    const float* __restrict__ x,
    const float* __restrict__ wgt,
    float* __restrict__ out)
{
    __shared__ float sw[16 * KK * KK * 8];
    const int tid = threadIdx.x;
    for (int idx = tid; idx < 8 * 16 * KK * KK; idx += 256) {
        int n  = idx / (16 * KK * KK);
        int rm = idx - n * (16 * KK * KK);
        int dc = rm / (KK * KK);
        int r2 = rm - dc * (KK * KK);
        int ky = r2 / KK;
        int kx = r2 - ky * KK;
        sw[((dc * KK + kx) * KK + ky) * 8 + n] = wgt[idx];
    }
    __syncthreads();

    const int bid = blockIdx.x;
    const int b   = bid >> 6;
    const int j   = (bid >> 1) & 31;
    const int yh  = bid & 1;
    const int xw  = tid & 31;
    const int yg  = tid >> 5;
    const int y_base = yh * 16 + yg * 2;

    int rows[10];
    #pragma unroll
    for (int i = 0; i < 10; ++i)
        rows[i] = ((y_base + 24 + i) & 31) << 5;

    float acc[8][2];
    #pragma unroll
    for (int n = 0; n < 8; ++n) { acc[n][0] = 0.f; acc[n][1] = 0.f; }

    const int c0 = 4 * j;
    #pragma unroll 1
    for (int dc = 0; dc < 16; ++dc) {
        const int c_src = (c0 - dc) & 127;
        const float* bx = x + (((size_t)b * 128 + c_src) << 10);
        #pragma unroll 1
        for (int kx = 0; kx < KK; ++kx) {
            const int x_col = (xw - kx) & 31;
            float win[10];
            #pragma unroll
            for (int i = 0; i < 10; ++i)
                win[i] = bx[rows[i] + x_col];
            const float4* wp = (const float4*)&sw[((dc * KK + kx) * KK) * 8];
            #pragma unroll
            for (int ky = 0; ky < KK; ++ky) {
                float4 wA = wp[2 * ky];
                float4 wB = wp[2 * ky + 1];
                float x0 = win[8 - ky];
                float x1 = win[9 - ky];
                acc[0][0] += x0 * wA.x; acc[0][1] += x1 * wA.x;
                acc[1][0] += x0 * wA.y; acc[1][1] += x1 * wA.y;
                acc[2][0] += x0 * wA.z; acc[2][1] += x1 * wA.z;
                acc[3][0] += x0 * wA.w; acc[3][1] += x1 * wA.w;
                acc[4][0] += x0 * wB.x; acc[4][1] += x1 * wB.x;
                acc[5][0] += x0 * wB.y; acc[5][1] += x1 * wB.y;
                acc[6][0] += x0 * wB.z; acc[6][1] += x1 * wB.z;
                acc[7][0] += x0 * wB.w; acc[7][1] += x1 * wB.w;
            }
        }
    }
    #pragma unroll
    for (int n = 0; n < 8; ++n) {
        float* op = out + ((((size_t)b * 256) + n * 32 + j) << 10) + (y_base << 5) + xw;
        op[0]  = acc[n][0];
        op[32] = acc[n][1];
    }
}

extern "C" void kernel_launch(void* const* d_in, const int* in_sizes, int n_in,
                              void* d_out, int out_size, void* d_ws, size_t ws_size,
                              hipStream_t stream) {
    const float* x   = (const float*)d_in[0];
    const float* w   = (const float*)d_in[1];
    float*       out = (float*)d_out;

    const size_t BG_BYTES = 41 * 4 * 16 * 8 * sizeof(unsigned short);  // 41984
    if (ws_size >= BG_BYTES) {
        unsigned short* Bg = (unsigned short*)d_ws;
        prep_w<<<82, 256, 0, stream>>>(w, Bg);
        fconv_mfma<<<1024, 256, 0, stream>>>(x, Bg, out);
    } else {
        fconv_fallback<<<2048, 256, 0, stream>>>(x, w, out);
    }
}

// Round 4
// 113.259 us; speedup vs baseline: 3.5832x; 1.0125x over previous
//
#include <hip/hip_runtime.h>

typedef __attribute__((ext_vector_type(4))) float  f32x4;
typedef __attribute__((ext_vector_type(8))) short  s16x8;

#define KK 9
#define NCHUNK 23   // ceil(45 tap-combos / 2); combos = (ky2 in 0..4) x (kx in 0..8)

__device__ inline unsigned short f2bf(float f) {
    union { float f; unsigned int u; } v; v.f = f;
    unsigned int u = v.u + 0x7FFFu + ((v.u >> 16) & 1u);   // RNE
    return (unsigned short)(u >> 16);
}

// ---------------------------------------------------------------------------
// prep_w: pack weights into B-fragment layout (bf16) in d_ws.
// Bg element index = ((c*4 + g)*16 + col)*8 + e
//   col = n + 8*t  (n = filter, t = ky parity slot)
//   g: pi = g>>1 (tap slot within chunk), half = g&1 (channel half)
//   combo q = 2c + pi -> ky2 = q/9, kx = q%9 ; ky = 2*ky2 + t
//   channel cp = half*8 + e ; dc = 15 - cp
//   value = wgt[n, dc, ky, kx]   (0 if q > 44 or ky > 8)
// ---------------------------------------------------------------------------
__global__ void prep_w(const float* __restrict__ wgt, unsigned short* __restrict__ Bg) {
    int idx = blockIdx.x * 256 + threadIdx.x;
    if (idx >= NCHUNK * 4 * 16 * 8) return;
    int e   = idx & 7;
    int col = (idx >> 3) & 15;
    int g   = (idx >> 7) & 3;
    int c   = idx >> 9;
    int pi   = g >> 1;
    int half = g & 1;
    int cp = half * 8 + e;
    int dc = 15 - cp;
    int q  = 2 * c + pi;
    int n  = col & 7;
    int t  = col >> 3;
    float val = 0.f;
    if (q <= 44) {
        int ky2 = q / 9;
        int kx  = q - 9 * ky2;
        int ky  = 2 * ky2 + t;
        if (ky <= 8)
            val = wgt[((n * 16 + dc) * KK + ky) * KK + kx];
    }
    Bg[idx] = f2bf(val);
}

// ---------------------------------------------------------------------------
// Main MFMA kernel: one block per (b, j). M=1024 spatial, N=16 = 8n x 2t,
// K = 23 chunks x 32 (= 2 tap-combos x 16 channels each).
// Column (n,t) result at dy contributes to out row y0+dy+t; merged in epilogue
// via shfl_xor(8) + one cross-wave LDS handoff (y circular mod 32).
// ---------------------------------------------------------------------------
__global__ __launch_bounds__(256) void fconv_mfma(
    const float* __restrict__ x,
    const unsigned short* __restrict__ Bg,
    float* __restrict__ out)
{
    __shared__ char smem[32768 + 4096];    // 32KB x-tile + 4KB handoff
    char*  smb     = smem;
    float* handoff = (float*)(smem + 32768);

    const int tid = threadIdx.x;
    const int b   = blockIdx.x >> 5;
    const int j   = blockIdx.x & 31;

    // ---- stage x tile: 16 channels (4j-15 .. 4j), bf16, [half][spatial][8ch] ----
    const float* xb = x + ((size_t)b << 17);   // b * 128*1024
    int choff[16];
    #pragma unroll
    for (int i = 0; i < 16; ++i)
        choff[i] = ((4 * j - 15 + i) & 127) << 10;   // uniform -> SGPR

    #pragma unroll
    for (int i = 0; i < 4; ++i) {
        int cell = i * 256 + tid;                    // spatial index y*32+w
        #pragma unroll
        for (int h = 0; h < 2; ++h) {
            union { unsigned short u16[8]; uint4 v; } pk;
            #pragma unroll
            for (int e = 0; e < 8; ++e)
                pk.u16[e] = f2bf(xb[choff[h * 8 + e] + cell]);
            *(uint4*)(smb + h * 16384 + cell * 16) = pk.v;
        }
    }
    __syncthreads();

    // ---- per-lane decomposition ----
    const int lane = tid & 63;
    const int wave = tid >> 6;        // 4 waves, y0 = wave*8
    const int r    = lane & 15;       // A row (w offset) / B col
    const int g    = lane >> 4;       // k-group 0..3
    const int half = g & 1;           // channel half
    const int pi   = g >> 1;          // tap slot within chunk
    const int y0   = wave * 8;

    f32x4 acc[8][2];
    #pragma unroll
    for (int dy = 0; dy < 8; ++dy) { acc[dy][0] = (f32x4)0.f; acc[dy][1] = (f32x4)0.f; }

    // per-lane B pointer: byte offset = chunk*1024 + (g*16+col)*16
    const char* bptr = (const char*)Bg + ((g * 16 + r) << 4);
    s16x8 bfrag = *(const s16x8*)(bptr);

    #pragma unroll 1
    for (int c = 0; c < NCHUNK; ++c) {
        int q   = 2 * c + pi;
        int ky2 = q / 9;
        int kx  = q - 9 * ky2;
        int wr  = (r - kx) & 31;
        int yb  = (y0 - 2 * ky2) & 31;
        int abase = (half << 14) + (wr << 4);

        int cn = (c < NCHUNK - 1) ? c + 1 : NCHUNK - 1;
        s16x8 bnext = *(const s16x8*)(bptr + (cn << 10));

        #pragma unroll
        for (int dy = 0; dy < 8; ++dy) {
            int yy = (yb + dy) & 31;
            int ra = abase + (yy << 9);
            s16x8 a0 = *(const s16x8*)(smb + ra);
            s16x8 a1 = *(const s16x8*)(smb + (ra ^ 256));
            acc[dy][0] = __builtin_amdgcn_mfma_f32_16x16x32_bf16(a0, bfrag, acc[dy][0], 0, 0, 0);
            acc[dy][1] = __builtin_amdgcn_mfma_f32_16x16x32_bf16(a1, bfrag, acc[dy][1], 0, 0, 0);
        }
        bfrag = bnext;
    }

    // ---- epilogue ----
    // lane holds D[row][col=r]: r<8 -> (n=r, t=0); r>=8 -> (n=r-8, t=1).
    // out[n, y0+dy'] = acc[dy'](t0) + acc[dy'-1](t1);  acc[-1](t1) from prev wave.
    float recv[8][2][4];
    #pragma unroll
    for (int dy = 0; dy < 8; ++dy)
        #pragma unroll
        for (int h = 0; h < 2; ++h)
            #pragma unroll
            for (int i = 0; i < 4; ++i)
                recv[dy][h][i] = __shfl_xor(acc[dy][h][i], 8);

    // cross-wave handoff of recv[7] (contribution to y0+8 = next wave's row 0)
    if (r < 8) {
        #pragma unroll
        for (int h = 0; h < 2; ++h)
            *(f32x4*)&handoff[wave * 256 + r * 32 + h * 16 + g * 4] = *(f32x4*)recv[7][h];
    }
    __syncthreads();

    if (r < 8) {
        const int pw = (wave + 3) & 3;
        f32x4 prev[2];
        #pragma unroll
        for (int h = 0; h < 2; ++h)
            prev[h] = *(f32x4*)&handoff[pw * 256 + r * 32 + h * 16 + g * 4];

        float* ob = out + (((size_t)(b * 256 + r * 32 + j)) << 10) + (g << 2);
        #pragma unroll
        for (int dy = 0; dy < 8; ++dy) {
            #pragma unroll
            for (int h = 0; h < 2; ++h) {
                f32x4 t1 = (dy == 0) ? prev[h] : *(f32x4*)recv[dy - 1][h];
                f32x4 v  = acc[dy][h] + t1;
                *(f32x4*)(ob + (y0 + dy) * 32 + h * 16) = v;
            }
        }
    }
}

// ---------------------------------------------------------------------------
// Fallback (round-1 fp32 VALU kernel) if workspace is too small.
// ---------------------------------------------------------------------------
__global__ __launch_bounds__(256, 2) void fconv_fallback(
    const float* __restrict__ x,
    const float* __restrict__ wgt,
    float* __restrict__ out)
{
    __shared__ float sw[16 * KK * KK * 8];
    const int tid = threadIdx.x;
    for (int idx = tid; idx < 8 * 16 * KK * KK; idx += 256) {
        int n  = idx / (16 * KK * KK);
        int rm = idx - n * (16 * KK * KK);
        int dc = rm / (KK * KK);
        int r2 = rm - dc * (KK * KK);
        int ky = r2 / KK;
        int kx = r2 - ky * KK;
        sw[((dc * KK + kx) * KK + ky) * 8 + n] = wgt[idx];
    }
    __syncthreads();

    const int bid = blockIdx.x;
    const int b   = bid >> 6;
    const int j   = (bid >> 1) & 31;
    const int yh  = bid & 1;
    const int xw  = tid & 31;
    const int yg  = tid >> 5;
    const int y_base = yh * 16 + yg * 2;

    int rows[10];
    #pragma unroll
    for (int i = 0; i < 10; ++i)
        rows[i] = ((y_base + 24 + i) & 31) << 5;

    float acc[8][2];
    #pragma unroll
    for (int n = 0; n < 8; ++n) { acc[n][0] = 0.f; acc[n][1] = 0.f; }

    const int c0 = 4 * j;
    #pragma unroll 1
    for (int dc = 0; dc < 16; ++dc) {
        const int c_src = (c0 - dc) & 127;
        const float* bx = x + (((size_t)b * 128 + c_src) << 10);
        #pragma unroll 1
        for (int kx = 0; kx < KK; ++kx) {
            const int x_col = (xw - kx) & 31;
            float win[10];
            #pragma unroll
            for (int i = 0; i < 10; ++i)
                win[i] = bx[rows[i] + x_col];
            const float4* wp = (const float4*)&sw[((dc * KK + kx) * KK) * 8];
            #pragma unroll
            for (int ky = 0; ky < KK; ++ky) {
                float4 wA = wp[2 * ky];
                float4 wB = wp[2 * ky + 1];
                float x0 = win[8 - ky];
                float x1 = win[9 - ky];
                acc[0][0] += x0 * wA.x; acc[0][1] += x1 * wA.x;
                acc[1][0] += x0 * wA.y; acc[1][1] += x1 * wA.y;
                acc[2][0] += x0 * wA.z; acc[2][1] += x1 * wA.z;
                acc[3][0] += x0 * wA.w; acc[3][1] += x1 * wA.w;
                acc[4][0] += x0 * wB.x; acc[4][1] += x1 * wB.x;
                acc[5][0] += x0 * wB.y; acc[5][1] += x1 * wB.y;
                acc[6][0] += x0 * wB.z; acc[6][1] += x1 * wB.z;
                acc[7][0] += x0 * wB.w; acc[7][1] += x1 * wB.w;
            }
        }
    }
    #pragma unroll
    for (int n = 0; n < 8; ++n) {
        float* op = out + ((((size_t)b * 256) + n * 32 + j) << 10) + (y_base << 5) + xw;
        op[0]  = acc[n][0];
        op[32] = acc[n][1];
    }
}

extern "C" void kernel_launch(void* const* d_in, const int* in_sizes, int n_in,
                              void* d_out, int out_size, void* d_ws, size_t ws_size,
                              hipStream_t stream) {
    const float* x   = (const float*)d_in[0];
    const float* w   = (const float*)d_in[1];
    float*       out = (float*)d_out;

    const size_t BG_BYTES = NCHUNK * 4 * 16 * 8 * sizeof(unsigned short);  // 23552
    if (ws_size >= BG_BYTES) {
        unsigned short* Bg = (unsigned short*)d_ws;
        prep_w<<<46, 256, 0, stream>>>(w, Bg);
        fconv_mfma<<<1024, 256, 0, stream>>>(x, Bg, out);
    } else {
        fconv_fallback<<<2048, 256, 0, stream>>>(x, w, out);
    }
}

// Round 5
// 113.039 us; speedup vs baseline: 3.5901x; 1.0019x over previous
//
#include <hip/hip_runtime.h>

typedef __attribute__((ext_vector_type(4)))  float f32x4;
typedef __attribute__((ext_vector_type(16))) float f32x16;
typedef __attribute__((ext_vector_type(8)))  short s16x8;

#define KK 9
#define NCHUNK 23       // tier-2 fallback chunk count

__device__ inline unsigned short f2bf(float f) {
    union { float f; unsigned int u; } v; v.f = f;
    unsigned int u = v.u + 0x7FFFu + ((v.u >> 16) & 1u);   // RNE
    return (unsigned short)(u >> 16);
}

// ===========================================================================
// TIER 1: 32x32x16 MFMA, columns = (n, p) with p = output-row-in-y-group.
// ===========================================================================

// Bg[( (chunk*64 + lane)*8 + e )]:
//   chunk = kx*12 + s  (kx 0..8, s 0..11, ky' = s-3)
//   lane: col = lane&31 = n + 8p ; khalf = lane>>5
//   k = khalf*8 + e -> cp ; dc = 15-cp ; ky = (s-3)+p
//   val = wgt[n, dc, ky, kx] if 0<=ky<=8 else 0
__global__ void prep_w32(const float* __restrict__ wgt, unsigned short* __restrict__ Bg) {
    int idx = blockIdx.x * 256 + threadIdx.x;
    if (idx >= 108 * 64 * 8) return;
    int e     = idx & 7;
    int lanei = (idx >> 3) & 63;
    int chunk = idx >> 9;
    int col   = lanei & 31;
    int khalf = lanei >> 5;
    int n  = col & 7;
    int p  = col >> 3;
    int kx = chunk / 12;
    int s  = chunk - 12 * kx;
    int ky = s - 3 + p;
    int cp = khalf * 8 + e;
    int dc = 15 - cp;
    float val = 0.f;
    if (ky >= 0 && ky <= 8)
        val = wgt[((n * 16 + dc) * KK + ky) * KK + kx];
    Bg[idx] = f2bf(val);
}

// One block per (b, j): 512 threads = 8 waves, wave handles y-group g = wave
// (output rows 4g..4g+3).  Per chunk: one ds_read_b128 (A: 8ch at [y', w-kx])
// + one 32x32x16 MFMA.  D[row=w][col=(n,p)] is the final output directly.
__global__ __launch_bounds__(512, 8) void fconv_mfma32(
    const float* __restrict__ x,
    const unsigned short* __restrict__ Bg,
    float* __restrict__ out)
{
    __shared__ char smb[32768];   // [half][cell=y*32+w][8ch] bf16

    const int tid = threadIdx.x;
    const int b   = blockIdx.x >> 5;
    const int j   = blockIdx.x & 31;

    // ---- stage x tile: 16 channels (4j-15 .. 4j) ----
    const float* xb = x + ((size_t)b << 17);
    int choff[16];
    #pragma unroll
    for (int i = 0; i < 16; ++i)
        choff[i] = ((4 * j - 15 + i) & 127) << 10;   // uniform -> SGPR

    #pragma unroll
    for (int i = 0; i < 2; ++i) {
        int cell = i * 512 + tid;
        #pragma unroll
        for (int h = 0; h < 2; ++h) {
            union { unsigned short u16[8]; uint4 v; } pk;
            #pragma unroll
            for (int e = 0; e < 8; ++e)
                pk.u16[e] = f2bf(xb[choff[h * 8 + e] + cell]);
            *(uint4*)(smb + h * 16384 + cell * 16) = pk.v;
        }
    }
    __syncthreads();

    const int lane  = tid & 63;
    const int wave  = tid >> 6;      // 8 waves, y-group = wave
    const int wrow  = lane & 31;     // A row = output w ; D col
    const int khalf = lane >> 5;     // channel half (k-group)
    const int g4    = wave * 4;

    f32x16 acc = (f32x16)0.f;
    const char* bp = (const char*)Bg + (lane << 4);

    #pragma unroll 1
    for (int kx = 0; kx < 9; ++kx) {
        const int abase = (khalf << 14) + (((wrow - kx) & 31) << 4);
        const char* bpk = bp + ((kx * 12) << 10);
        #pragma unroll
        for (int s = 0; s < 12; ++s) {
            int yp = (g4 + 3 - s) & 31;              // x row = 4g - ky'
            s16x8 a  = *(const s16x8*)(smb + abase + (yp << 9));
            s16x8 bb = *(const s16x8*)(bpk + (s << 10));
            acc = __builtin_amdgcn_mfma_f32_32x32x16_bf16(a, bb, acc, 0, 0, 0);
        }
    }

    // ---- store: D row = (reg&3)+8*(reg>>2)+4*khalf = w ; col = n+8p ----
    const int n = wrow & 7;
    const int p = wrow >> 3;
    float* ob = out + (((size_t)(b * 256 + n * 32 + j)) << 10)
                    + ((g4 + p) << 5) + 4 * khalf;
    #pragma unroll
    for (int q = 0; q < 4; ++q) {
        f32x4 v = { acc[4*q], acc[4*q+1], acc[4*q+2], acc[4*q+3] };
        *(f32x4*)(ob + q * 8) = v;
    }
}

// ===========================================================================
// TIER 2: round-4 16x16x32 ky-paired kernel (proven; needs only 23 KB ws).
// ===========================================================================
__global__ void prep_w(const float* __restrict__ wgt, unsigned short* __restrict__ Bg) {
    int idx = blockIdx.x * 256 + threadIdx.x;
    if (idx >= NCHUNK * 4 * 16 * 8) return;
    int e   = idx & 7;
    int col = (idx >> 3) & 15;
    int g   = (idx >> 7) & 3;
    int c   = idx >> 9;
    int pi   = g >> 1;
    int half = g & 1;
    int cp = half * 8 + e;
    int dc = 15 - cp;
    int q  = 2 * c + pi;
    int n  = col & 7;
    int t  = col >> 3;
    float val = 0.f;
    if (q <= 44) {
        int ky2 = q / 9;
        int kx  = q - 9 * ky2;
        int ky  = 2 * ky2 + t;
        if (ky <= 8)
            val = wgt[((n * 16 + dc) * KK + ky) * KK + kx];
    }
    Bg[idx] = f2bf(val);
}

__global__ __launch_bounds__(256) void fconv_mfma(
    const float* __restrict__ x,
    const unsigned short* __restrict__ Bg,
    float* __restrict__ out)
{
    __shared__ char smem[32768 + 4096];
    char*  smb     = smem;
    float* handoff = (float*)(smem + 32768);

    const int tid = threadIdx.x;
    const int b   = blockIdx.x >> 5;
    const int j   = blockIdx.x & 31;

    const float* xb = x + ((size_t)b << 17);
    int choff[16];
    #pragma unroll
    for (int i = 0; i < 16; ++i)
        choff[i] = ((4 * j - 15 + i) & 127) << 10;

    #pragma unroll
    for (int i = 0; i < 4; ++i) {
        int cell = i * 256 + tid;
        #pragma unroll
        for (int h = 0; h < 2; ++h) {
            union { unsigned short u16[8]; uint4 v; } pk;
            #pragma unroll
            for (int e = 0; e < 8; ++e)
                pk.u16[e] = f2bf(xb[choff[h * 8 + e] + cell]);
            *(uint4*)(smb + h * 16384 + cell * 16) = pk.v;
        }
    }
    __syncthreads();

    const int lane = tid & 63;
    const int wave = tid >> 6;
    const int r    = lane & 15;
    const int g    = lane >> 4;
    const int half = g & 1;
    const int pi   = g >> 1;
    const int y0   = wave * 8;

    f32x4 acc[8][2];
    #pragma unroll
    for (int dy = 0; dy < 8; ++dy) { acc[dy][0] = (f32x4)0.f; acc[dy][1] = (f32x4)0.f; }

    const char* bptr = (const char*)Bg + ((g * 16 + r) << 4);
    s16x8 bfrag = *(const s16x8*)(bptr);

    #pragma unroll 1
    for (int c = 0; c < NCHUNK; ++c) {
        int q   = 2 * c + pi;
        int ky2 = q / 9;
        int kx  = q - 9 * ky2;
        int wr  = (r - kx) & 31;
        int yb  = (y0 - 2 * ky2) & 31;
        int abase = (half << 14) + (wr << 4);

        int cn = (c < NCHUNK - 1) ? c + 1 : NCHUNK - 1;
        s16x8 bnext = *(const s16x8*)(bptr + (cn << 10));

        #pragma unroll
        for (int dy = 0; dy < 8; ++dy) {
            int yy = (yb + dy) & 31;
            int ra = abase + (yy << 9);
            s16x8 a0 = *(const s16x8*)(smb + ra);
            s16x8 a1 = *(const s16x8*)(smb + (ra ^ 256));
            acc[dy][0] = __builtin_amdgcn_mfma_f32_16x16x32_bf16(a0, bfrag, acc[dy][0], 0, 0, 0);
            acc[dy][1] = __builtin_amdgcn_mfma_f32_16x16x32_bf16(a1, bfrag, acc[dy][1], 0, 0, 0);
        }
        bfrag = bnext;
    }

    float recv[8][2][4];
    #pragma unroll
    for (int dy = 0; dy < 8; ++dy)
        #pragma unroll
        for (int h = 0; h < 2; ++h)
            #pragma unroll
            for (int i = 0; i < 4; ++i)
                recv[dy][h][i] = __shfl_xor(acc[dy][h][i], 8);

    if (r < 8) {
        #pragma unroll
        for (int h = 0; h < 2; ++h)
            *(f32x4*)&handoff[wave * 256 + r * 32 + h * 16 + g * 4] = *(f32x4*)recv[7][h];
    }
    __syncthreads();

    if (r < 8) {
        const int pw = (wave + 3) & 3;
        f32x4 prev[2];
        #pragma unroll
        for (int h = 0; h < 2; ++h)
            prev[h] = *(f32x4*)&handoff[pw * 256 + r * 32 + h * 16 + g * 4];

        float* ob = out + (((size_t)(b * 256 + r * 32 + j)) << 10) + (g << 2);
        #pragma unroll
        for (int dy = 0; dy < 8; ++dy) {
            #pragma unroll
            for (int h = 0; h < 2; ++h) {
                f32x4 t1 = (dy == 0) ? prev[h] : *(f32x4*)recv[dy - 1][h];
                f32x4 v  = acc[dy][h] + t1;
                *(f32x4*)(ob + (y0 + dy) * 32 + h * 16) = v;
            }
        }
    }
}

// ===========================================================================
// TIER 3: fp32 VALU fallback (no workspace needed).
// ===========================================================================
__global__ __launch_bounds__(256, 2) void fconv_fallback(
    const float* __restrict__ x,
    const float* __restrict__ wgt,
    float* __restrict__ out)
{
    __shared__ float sw[16 * KK * KK * 8];
    const int tid = threadIdx.x;
    for (int idx = tid; idx < 8 * 16 * KK * KK; idx += 256) {
        int n  = idx / (16 * KK * KK);
        int rm = idx - n * (16 * KK * KK);
        int dc = rm / (KK * KK);
        int r2 = rm - dc * (KK * KK);
        int ky = r2 / KK;
        int kx = r2 - ky * KK;
        sw[((dc * KK + kx) * KK + ky) * 8 + n] = wgt[idx];
    }
    __syncthreads();

    const int bid = blockIdx.x;
    const int b   = bid >> 6;
    const int j   = (bid >> 1) & 31;
    const int yh  = bid & 1;
    const int xw  = tid & 31;
    const int yg  = tid >> 5;
    const int y_base = yh * 16 + yg * 2;

    int rows[10];
    #pragma unroll
    for (int i = 0; i < 10; ++i)
        rows[i] = ((y_base + 24 + i) & 31) << 5;

    float acc[8][2];
    #pragma unroll
    for (int n = 0; n < 8; ++n) { acc[n][0] = 0.f; acc[n][1] = 0.f; }

    const int c0 = 4 * j;
    #pragma unroll 1
    for (int dc = 0; dc < 16; ++dc) {
        const int c_src = (c0 - dc) & 127;
        const float* bx = x + (((size_t)b * 128 + c_src) << 10);
        #pragma unroll 1
        for (int kx = 0; kx < KK; ++kx) {
            const int x_col = (xw - kx) & 31;
            float win[10];
            #pragma unroll
            for (int i = 0; i < 10; ++i)
                win[i] = bx[rows[i] + x_col];
            const float4* wp = (const float4*)&sw[((dc * KK + kx) * KK) * 8];
            #pragma unroll
            for (int ky = 0; ky < KK; ++ky) {
                float4 wA = wp[2 * ky];
                float4 wB = wp[2 * ky + 1];
                float x0 = win[8 - ky];
                float x1 = win[9 - ky];
                acc[0][0] += x0 * wA.x; acc[0][1] += x1 * wA.x;
                acc[1][0] += x0 * wA.y; acc[1][1] += x1 * wA.y;
                acc[2][0] += x0 * wA.z; acc[2][1] += x1 * wA.z;
                acc[3][0] += x0 * wA.w; acc[3][1] += x1 * wA.w;
                acc[4][0] += x0 * wB.x; acc[4][1] += x1 * wB.x;
                acc[5][0] += x0 * wB.y; acc[5][1] += x1 * wB.y;
                acc[6][0] += x0 * wB.z; acc[6][1] += x1 * wB.z;
                acc[7][0] += x0 * wB.w; acc[7][1] += x1 * wB.w;
            }
        }
    }
    #pragma unroll
    for (int n = 0; n < 8; ++n) {
        float* op = out + ((((size_t)b * 256) + n * 32 + j) << 10) + (y_base << 5) + xw;
        op[0]  = acc[n][0];
        op[32] = acc[n][1];
    }
}

extern "C" void kernel_launch(void* const* d_in, const int* in_sizes, int n_in,
                              void* d_out, int out_size, void* d_ws, size_t ws_size,
                              hipStream_t stream) {
    const float* x   = (const float*)d_in[0];
    const float* w   = (const float*)d_in[1];
    float*       out = (float*)d_out;

    const size_t BG32_BYTES = (size_t)108 * 64 * 8 * sizeof(unsigned short);  // 110592
    const size_t BG16_BYTES = (size_t)NCHUNK * 4 * 16 * 8 * sizeof(unsigned short);

    if (ws_size >= BG32_BYTES) {
        unsigned short* Bg = (unsigned short*)d_ws;
        prep_w32<<<216, 256, 0, stream>>>(w, Bg);
        fconv_mfma32<<<1024, 512, 0, stream>>>(x, Bg, out);
    } else if (ws_size >= BG16_BYTES) {
        unsigned short* Bg = (unsigned short*)d_ws;
        prep_w<<<46, 256, 0, stream>>>(w, Bg);
        fconv_mfma<<<1024, 256, 0, stream>>>(x, Bg, out);
    } else {
        fconv_fallback<<<2048, 256, 0, stream>>>(x, w, out);
    }
}

// Round 6
// 112.318 us; speedup vs baseline: 3.6132x; 1.0064x over previous
//
#include <hip/hip_runtime.h>

typedef __attribute__((ext_vector_type(4)))  float f32x4;
typedef __attribute__((ext_vector_type(16))) float f32x16;
typedef __attribute__((ext_vector_type(8)))  short s16x8;

#define KK 9
#define NCHUNK 23       // tier-2 fallback chunk count

__device__ inline unsigned short f2bf(float f) {
    union { float f; unsigned int u; } v; v.f = f;
    unsigned int u = v.u + 0x7FFFu + ((v.u >> 16) & 1u);   // RNE
    return (unsigned short)(u >> 16);
}

// ===========================================================================
// TIER 1: 32x32x16 MFMA, columns = (n, p) with p = output-row-in-y-group.
// ===========================================================================

// Bg[( (chunk*64 + lane)*8 + e )]:
//   chunk = kx*12 + s  (kx 0..8, s 0..11, ky' = s-3)
//   lane: col = lane&31 = n + 8p ; khalf = lane>>5
//   k = khalf*8 + e -> cp ; dc = 15-cp ; ky = (s-3)+p
//   val = wgt[n, dc, ky, kx] if 0<=ky<=8 else 0
__global__ void prep_w32(const float* __restrict__ wgt, unsigned short* __restrict__ Bg) {
    int idx = blockIdx.x * 256 + threadIdx.x;
    if (idx >= 108 * 64 * 8) return;
    int e     = idx & 7;
    int lanei = (idx >> 3) & 63;
    int chunk = idx >> 9;
    int col   = lanei & 31;
    int khalf = lanei >> 5;
    int n  = col & 7;
    int p  = col >> 3;
    int kx = chunk / 12;
    int s  = chunk - 12 * kx;
    int ky = s - 3 + p;
    int cp = khalf * 8 + e;
    int dc = 15 - cp;
    float val = 0.f;
    if (ky >= 0 && ky <= 8)
        val = wgt[((n * 16 + dc) * KK + ky) * KK + kx];
    Bg[idx] = f2bf(val);
}

// One block per (b, j): 512 threads = 8 waves, wave handles y-group g = wave.
// Per chunk: one ds_read_b128 (A) + one L2-resident global dwordx4 (B) + one
// 32x32x16 MFMA.  Explicit SW pipeline: A +1 chunk ahead, B +3 chunks ahead.
__global__ __launch_bounds__(512, 8) void fconv_mfma32(
    const float* __restrict__ x,
    const unsigned short* __restrict__ Bg,
    float* __restrict__ out)
{
    __shared__ char smb[32768];   // [half][cell=y*32+w][8ch] bf16

    const int tid = threadIdx.x;
    const int b   = blockIdx.x >> 5;
    const int j   = blockIdx.x & 31;

    // ---- stage x tile: 16 channels (4j-15 .. 4j) ----
    const float* xb = x + ((size_t)b << 17);
    int choff[16];
    #pragma unroll
    for (int i = 0; i < 16; ++i)
        choff[i] = ((4 * j - 15 + i) & 127) << 10;   // uniform -> SGPR

    #pragma unroll
    for (int i = 0; i < 2; ++i) {
        int cell = i * 512 + tid;
        #pragma unroll
        for (int h = 0; h < 2; ++h) {
            union { unsigned short u16[8]; uint4 v; } pk;
            #pragma unroll
            for (int e = 0; e < 8; ++e)
                pk.u16[e] = f2bf(xb[choff[h * 8 + e] + cell]);
            *(uint4*)(smb + h * 16384 + cell * 16) = pk.v;
        }
    }
    __syncthreads();

    const int lane  = tid & 63;
    const int wave  = tid >> 6;      // 8 waves, y-group = wave
    const int wrow  = lane & 31;     // A row = output w ; D col
    const int khalf = lane >> 5;     // channel half (k-group)
    const int g4    = wave * 4;

    f32x16 acc = (f32x16)0.f;
    const char* bp = (const char*)Bg + (lane << 4);
    const char* ab = smb + (khalf << 14);

    // A address for flat chunk c = kx*12 + s :
    //   ab + ((wrow-kx)&31)<<4 + ((g4+3-s)&31)<<9
    #define AADDR(c_) ((const s16x8*)(ab + ((((wrow - ((c_) / 12)) & 31)) << 4) \
                                         + ((((g4 + 3 - ((c_) % 12)) & 31)) << 9)))

    s16x8 a0 = *AADDR(0);
    s16x8 b0 = *(const s16x8*)(bp);
    s16x8 b1 = *(const s16x8*)(bp + (1 << 10));
    s16x8 b2 = *(const s16x8*)(bp + (2 << 10));

    #pragma unroll 4
    for (int c = 0; c < 108; ++c) {
        int ca = (c + 1 < 108) ? c + 1 : 107;
        int cb = (c + 3 < 108) ? c + 3 : 107;
        s16x8 an = *AADDR(ca);
        s16x8 bn = *(const s16x8*)(bp + (cb << 10));
        acc = __builtin_amdgcn_mfma_f32_32x32x16_bf16(a0, b0, acc, 0, 0, 0);
        a0 = an;
        b0 = b1; b1 = b2; b2 = bn;
    }
    #undef AADDR

    // ---- store: D row = (reg&3)+8*(reg>>2)+4*khalf = w ; col = n+8p ----
    const int n = wrow & 7;
    const int p = wrow >> 3;
    float* ob = out + (((size_t)(b * 256 + n * 32 + j)) << 10)
                    + ((g4 + p) << 5) + 4 * khalf;
    #pragma unroll
    for (int q = 0; q < 4; ++q) {
        f32x4 v = { acc[4*q], acc[4*q+1], acc[4*q+2], acc[4*q+3] };
        *(f32x4*)(ob + q * 8) = v;
    }
}

// ===========================================================================
// TIER 2: 16x16x32 ky-paired kernel (proven; needs only 23 KB ws).
// ===========================================================================
__global__ void prep_w(const float* __restrict__ wgt, unsigned short* __restrict__ Bg) {
    int idx = blockIdx.x * 256 + threadIdx.x;
    if (idx >= NCHUNK * 4 * 16 * 8) return;
    int e   = idx & 7;
    int col = (idx >> 3) & 15;
    int g   = (idx >> 7) & 3;
    int c   = idx >> 9;
    int pi   = g >> 1;
    int half = g & 1;
    int cp = half * 8 + e;
    int dc = 15 - cp;
    int q  = 2 * c + pi;
    int n  = col & 7;
    int t  = col >> 3;
    float val = 0.f;
    if (q <= 44) {
        int ky2 = q / 9;
        int kx  = q - 9 * ky2;
        int ky  = 2 * ky2 + t;
        if (ky <= 8)
            val = wgt[((n * 16 + dc) * KK + ky) * KK + kx];
    }
    Bg[idx] = f2bf(val);
}

__global__ __launch_bounds__(256) void fconv_mfma(
    const float* __restrict__ x,
    const unsigned short* __restrict__ Bg,
    float* __restrict__ out)
{
    __shared__ char smem[32768 + 4096];
    char*  smb     = smem;
    float* handoff = (float*)(smem + 32768);

    const int tid = threadIdx.x;
    const int b   = blockIdx.x >> 5;
    const int j   = blockIdx.x & 31;

    const float* xb = x + ((size_t)b << 17);
    int choff[16];
    #pragma unroll
    for (int i = 0; i < 16; ++i)
        choff[i] = ((4 * j - 15 + i) & 127) << 10;

    #pragma unroll
    for (int i = 0; i < 4; ++i) {
        int cell = i * 256 + tid;
        #pragma unroll
        for (int h = 0; h < 2; ++h) {
            union { unsigned short u16[8]; uint4 v; } pk;
            #pragma unroll
            for (int e = 0; e < 8; ++e)
                pk.u16[e] = f2bf(xb[choff[h * 8 + e] + cell]);
            *(uint4*)(smb + h * 16384 + cell * 16) = pk.v;
        }
    }
    __syncthreads();

    const int lane = tid & 63;
    const int wave = tid >> 6;
    const int r    = lane & 15;
    const int g    = lane >> 4;
    const int half = g & 1;
    const int pi   = g >> 1;
    const int y0   = wave * 8;

    f32x4 acc[8][2];
    #pragma unroll
    for (int dy = 0; dy < 8; ++dy) { acc[dy][0] = (f32x4)0.f; acc[dy][1] = (f32x4)0.f; }

    const char* bptr = (const char*)Bg + ((g * 16 + r) << 4);
    s16x8 bfrag = *(const s16x8*)(bptr);

    #pragma unroll 1
    for (int c = 0; c < NCHUNK; ++c) {
        int q   = 2 * c + pi;
        int ky2 = q / 9;
        int kx  = q - 9 * ky2;
        int wr  = (r - kx) & 31;
        int yb  = (y0 - 2 * ky2) & 31;
        int abase = (half << 14) + (wr << 4);

        int cn = (c < NCHUNK - 1) ? c + 1 : NCHUNK - 1;
        s16x8 bnext = *(const s16x8*)(bptr + (cn << 10));

        #pragma unroll
        for (int dy = 0; dy < 8; ++dy) {
            int yy = (yb + dy) & 31;
            int ra = abase + (yy << 9);
            s16x8 a0 = *(const s16x8*)(smb + ra);
            s16x8 a1 = *(const s16x8*)(smb + (ra ^ 256));
            acc[dy][0] = __builtin_amdgcn_mfma_f32_16x16x32_bf16(a0, bfrag, acc[dy][0], 0, 0, 0);
            acc[dy][1] = __builtin_amdgcn_mfma_f32_16x16x32_bf16(a1, bfrag, acc[dy][1], 0, 0, 0);
        }
        bfrag = bnext;
    }

    float recv[8][2][4];
    #pragma unroll
    for (int dy = 0; dy < 8; ++dy)
        #pragma unroll
        for (int h = 0; h < 2; ++h)
            #pragma unroll
            for (int i = 0; i < 4; ++i)
                recv[dy][h][i] = __shfl_xor(acc[dy][h][i], 8);

    if (r < 8) {
        #pragma unroll
        for (int h = 0; h < 2; ++h)
            *(f32x4*)&handoff[wave * 256 + r * 32 + h * 16 + g * 4] = *(f32x4*)recv[7][h];
    }
    __syncthreads();

    if (r < 8) {
        const int pw = (wave + 3) & 3;
        f32x4 prev[2];
        #pragma unroll
        for (int h = 0; h < 2; ++h)
            prev[h] = *(f32x4*)&handoff[pw * 256 + r * 32 + h * 16 + g * 4];

        float* ob = out + (((size_t)(b * 256 + r * 32 + j)) << 10) + (g << 2);
        #pragma unroll
        for (int dy = 0; dy < 8; ++dy) {
            #pragma unroll
            for (int h = 0; h < 2; ++h) {
                f32x4 t1 = (dy == 0) ? prev[h] : *(f32x4*)recv[dy - 1][h];
                f32x4 v  = acc[dy][h] + t1;
                *(f32x4*)(ob + (y0 + dy) * 32 + h * 16) = v;
            }
        }
    }
}

// ===========================================================================
// TIER 3: fp32 VALU fallback (no workspace needed).
// ===========================================================================
__global__ __launch_bounds__(256, 2) void fconv_fallback(
    const float* __restrict__ x,
    const float* __restrict__ wgt,
    float* __restrict__ out)
{
    __shared__ float sw[16 * KK * KK * 8];
    const int tid = threadIdx.x;
    for (int idx = tid; idx < 8 * 16 * KK * KK; idx += 256) {
        int n  = idx / (16 * KK * KK);
        int rm = idx - n * (16 * KK * KK);
        int dc = rm / (KK * KK);
        int r2 = rm - dc * (KK * KK);
        int ky = r2 / KK;
        int kx = r2 - ky * KK;
        sw[((dc * KK + kx) * KK + ky) * 8 + n] = wgt[idx];
    }
    __syncthreads();

    const int bid = blockIdx.x;
    const int b   = bid >> 6;
    const int j   = (bid >> 1) & 31;
    const int yh  = bid & 1;
    const int xw  = tid & 31;
    const int yg  = tid >> 5;
    const int y_base = yh * 16 + yg * 2;

    int rows[10];
    #pragma unroll
    for (int i = 0; i < 10; ++i)
        rows[i] = ((y_base + 24 + i) & 31) << 5;

    float acc[8][2];
    #pragma unroll
    for (int n = 0; n < 8; ++n) { acc[n][0] = 0.f; acc[n][1] = 0.f; }

    const int c0 = 4 * j;
    #pragma unroll 1
    for (int dc = 0; dc < 16; ++dc) {
        const int c_src = (c0 - dc) & 127;
        const float* bx = x + (((size_t)b * 128 + c_src) << 10);
        #pragma unroll 1
        for (int kx = 0; kx < KK; ++kx) {
            const int x_col = (xw - kx) & 31;
            float win[10];
            #pragma unroll
            for (int i = 0; i < 10; ++i)
                win[i] = bx[rows[i] + x_col];
            const float4* wp = (const float4*)&sw[((dc * KK + kx) * KK) * 8];
            #pragma unroll
            for (int ky = 0; ky < KK; ++ky) {
                float4 wA = wp[2 * ky];
                float4 wB = wp[2 * ky + 1];
                float x0 = win[8 - ky];
                float x1 = win[9 - ky];
                acc[0][0] += x0 * wA.x; acc[0][1] += x1 * wA.x;
                acc[1][0] += x0 * wA.y; acc[1][1] += x1 * wA.y;
                acc[2][0] += x0 * wA.z; acc[2][1] += x1 * wA.z;
                acc[3][0] += x0 * wA.w; acc[3][1] += x1 * wA.w;
                acc[4][0] += x0 * wB.x; acc[4][1] += x1 * wB.x;
                acc[5][0] += x0 * wB.y; acc[5][1] += x1 * wB.y;
                acc[6][0] += x0 * wB.z; acc[6][1] += x1 * wB.z;
                acc[7][0] += x0 * wB.w; acc[7][1] += x1 * wB.w;
            }
        }
    }
    #pragma unroll
    for (int n = 0; n < 8; ++n) {
        float* op = out + ((((size_t)b * 256) + n * 32 + j) << 10) + (y_base << 5) + xw;
        op[0]  = acc[n][0];
        op[32] = acc[n][1];
    }
}

extern "C" void kernel_launch(void* const* d_in, const int* in_sizes, int n_in,
                              void* d_out, int out_size, void* d_ws, size_t ws_size,
                              hipStream_t stream) {
    const float* x   = (const float*)d_in[0];
    const float* w   = (const float*)d_in[1];
    float*       out = (float*)d_out;

    const size_t BG32_BYTES = (size_t)108 * 64 * 8 * sizeof(unsigned short);  // 110592
    const size_t BG16_BYTES = (size_t)NCHUNK * 4 * 16 * 8 * sizeof(unsigned short);

    if (ws_size >= BG32_BYTES) {
        unsigned short* Bg = (unsigned short*)d_ws;
        prep_w32<<<216, 256, 0, stream>>>(w, Bg);
        fconv_mfma32<<<1024, 512, 0, stream>>>(x, Bg, out);
    } else if (ws_size >= BG16_BYTES) {
        unsigned short* Bg = (unsigned short*)d_ws;
        prep_w<<<46, 256, 0, stream>>>(w, Bg);
        fconv_mfma<<<1024, 256, 0, stream>>>(x, Bg, out);
    } else {
        fconv_fallback<<<2048, 256, 0, stream>>>(x, w, out);
    }
}

// Round 7
// 106.872 us; speedup vs baseline: 3.7973x; 1.0510x over previous
//
#include <hip/hip_runtime.h>

typedef __attribute__((ext_vector_type(4)))  float f32x4;
typedef __attribute__((ext_vector_type(16))) float f32x16;
typedef __attribute__((ext_vector_type(8)))  short s16x8;

#define KK 9
#define NCHUNK 23       // tier-2 fallback chunk count

__device__ inline unsigned short f2bf(float f) {
    union { float f; unsigned int u; } v; v.f = f;
    unsigned int u = v.u + 0x7FFFu + ((v.u >> 16) & 1u);   // RNE
    return (unsigned short)(u >> 16);
}

// ===========================================================================
// TIER 1: 32x32x16 MFMA, columns = (n, p) with p = output-row-in-y-group.
// Each block handles TWO j values (jp, jp+16) -> every B fragment feeds 2
// MFMAs, halving the vector-memory B path.
// ===========================================================================

// Bg[( (chunk*64 + lane)*8 + e )]:
//   chunk = kx*12 + s  (kx 0..8, s 0..11, ky' = s-3)
//   lane: col = lane&31 = n + 8p ; khalf = lane>>5
//   k = khalf*8 + e -> cp ; dc = 15-cp ; ky = (s-3)+p
//   val = wgt[n, dc, ky, kx] if 0<=ky<=8 else 0
__global__ void prep_w32(const float* __restrict__ wgt, unsigned short* __restrict__ Bg) {
    int idx = blockIdx.x * 256 + threadIdx.x;
    if (idx >= 108 * 64 * 8) return;
    int e     = idx & 7;
    int lanei = (idx >> 3) & 63;
    int chunk = idx >> 9;
    int col   = lanei & 31;
    int khalf = lanei >> 5;
    int n  = col & 7;
    int p  = col >> 3;
    int kx = chunk / 12;
    int s  = chunk - 12 * kx;
    int ky = s - 3 + p;
    int cp = khalf * 8 + e;
    int dc = 15 - cp;
    float val = 0.f;
    if (ky >= 0 && ky <= 8)
        val = wgt[((n * 16 + dc) * KK + ky) * KK + kx];
    Bg[idx] = f2bf(val);
}

// 512 threads = 8 waves; wave = y-group g (rows 4g..4g+3) for BOTH j tiles.
// Per (kx): batch-load 12 B fragments (statically-indexed regs), then 12
// unrolled steps of {2x ds_read_b128 (tile0 / tile1 via offset imm) + 2 MFMA}.
__global__ __launch_bounds__(512, 4) void fconv_mfma32(
    const float* __restrict__ x,
    const unsigned short* __restrict__ Bg,
    float* __restrict__ out)
{
    __shared__ char smb[65536];   // [tile][half][cell=y*32+w][8ch] bf16

    const int tid = threadIdx.x;
    const int b   = blockIdx.x >> 4;
    const int jp  = blockIdx.x & 15;      // j0 = jp, j1 = jp + 16

    // ---- stage two x tiles: 16 channels each (4j-15 .. 4j) ----
    const float* xb = x + ((size_t)b << 17);
    #pragma unroll
    for (int t = 0; t < 2; ++t) {
        const int j = jp + t * 16;
        int choff[16];
        #pragma unroll
        for (int i = 0; i < 16; ++i)
            choff[i] = ((4 * j - 15 + i) & 127) << 10;   // uniform -> SGPR

        #pragma unroll
        for (int i = 0; i < 2; ++i) {
            int cell = i * 512 + tid;
            #pragma unroll
            for (int h = 0; h < 2; ++h) {
                union { unsigned short u16[8]; uint4 v; } pk;
                #pragma unroll
                for (int e = 0; e < 8; ++e)
                    pk.u16[e] = f2bf(xb[choff[h * 8 + e] + cell]);
                *(uint4*)(smb + t * 32768 + h * 16384 + cell * 16) = pk.v;
            }
        }
    }
    __syncthreads();

    const int lane  = tid & 63;
    const int wave  = tid >> 6;      // 8 waves, y-group = wave
    const int wrow  = lane & 31;     // A row = output w ; D col
    const int khalf = lane >> 5;     // channel half (k-group)
    const int g4    = wave * 4;

    f32x16 acc0 = (f32x16)0.f;
    f32x16 acc1 = (f32x16)0.f;
    const char* bp = (const char*)Bg + (lane << 4);

    #pragma unroll 1
    for (int kx = 0; kx < 9; ++kx) {
        const int abase = (khalf << 14) + (((wrow - kx) & 31) << 4);
        const char* bpk = bp + kx * 12288;

        s16x8 bb[12];
        #pragma unroll
        for (int s = 0; s < 12; ++s)
            bb[s] = *(const s16x8*)(bpk + (s << 10));

        #pragma unroll
        for (int s = 0; s < 12; ++s) {
            int yp = (g4 + 3 - s) & 31;              // x row = 4g - ky'
            const char* ap = smb + abase + (yp << 9);
            s16x8 a0 = *(const s16x8*)(ap);
            s16x8 a1 = *(const s16x8*)(ap + 32768);
            acc0 = __builtin_amdgcn_mfma_f32_32x32x16_bf16(a0, bb[s], acc0, 0, 0, 0);
            acc1 = __builtin_amdgcn_mfma_f32_32x32x16_bf16(a1, bb[s], acc1, 0, 0, 0);
        }
    }

    // ---- store: D row = (reg&3)+8*(reg>>2)+4*khalf = w ; col = n+8p ----
    const int n = wrow & 7;
    const int p = wrow >> 3;
    {
        float* ob = out + (((size_t)(b * 256 + n * 32 + jp)) << 10)
                        + ((g4 + p) << 5) + 4 * khalf;
        #pragma unroll
        for (int q = 0; q < 4; ++q) {
            f32x4 v = { acc0[4*q], acc0[4*q+1], acc0[4*q+2], acc0[4*q+3] };
            *(f32x4*)(ob + q * 8) = v;
        }
    }
    {
        float* ob = out + (((size_t)(b * 256 + n * 32 + jp + 16)) << 10)
                        + ((g4 + p) << 5) + 4 * khalf;
        #pragma unroll
        for (int q = 0; q < 4; ++q) {
            f32x4 v = { acc1[4*q], acc1[4*q+1], acc1[4*q+2], acc1[4*q+3] };
            *(f32x4*)(ob + q * 8) = v;
        }
    }
}

// ===========================================================================
// TIER 2: 16x16x32 ky-paired kernel (proven; needs only 23 KB ws).
// ===========================================================================
__global__ void prep_w(const float* __restrict__ wgt, unsigned short* __restrict__ Bg) {
    int idx = blockIdx.x * 256 + threadIdx.x;
    if (idx >= NCHUNK * 4 * 16 * 8) return;
    int e   = idx & 7;
    int col = (idx >> 3) & 15;
    int g   = (idx >> 7) & 3;
    int c   = idx >> 9;
    int pi   = g >> 1;
    int half = g & 1;
    int cp = half * 8 + e;
    int dc = 15 - cp;
    int q  = 2 * c + pi;
    int n  = col & 7;
    int t  = col >> 3;
    float val = 0.f;
    if (q <= 44) {
        int ky2 = q / 9;
        int kx  = q - 9 * ky2;
        int ky  = 2 * ky2 + t;
        if (ky <= 8)
            val = wgt[((n * 16 + dc) * KK + ky) * KK + kx];
    }
    Bg[idx] = f2bf(val);
}

__global__ __launch_bounds__(256) void fconv_mfma(
    const float* __restrict__ x,
    const unsigned short* __restrict__ Bg,
    float* __restrict__ out)
{
    __shared__ char smem[32768 + 4096];
    char*  smb     = smem;
    float* handoff = (float*)(smem + 32768);

    const int tid = threadIdx.x;
    const int b   = blockIdx.x >> 5;
    const int j   = blockIdx.x & 31;

    const float* xb = x + ((size_t)b << 17);
    int choff[16];
    #pragma unroll
    for (int i = 0; i < 16; ++i)
        choff[i] = ((4 * j - 15 + i) & 127) << 10;

    #pragma unroll
    for (int i = 0; i < 4; ++i) {
        int cell = i * 256 + tid;
        #pragma unroll
        for (int h = 0; h < 2; ++h) {
            union { unsigned short u16[8]; uint4 v; } pk;
            #pragma unroll
            for (int e = 0; e < 8; ++e)
                pk.u16[e] = f2bf(xb[choff[h * 8 + e] + cell]);
            *(uint4*)(smb + h * 16384 + cell * 16) = pk.v;
        }
    }
    __syncthreads();

    const int lane = tid & 63;
    const int wave = tid >> 6;
    const int r    = lane & 15;
    const int g    = lane >> 4;
    const int half = g & 1;
    const int pi   = g >> 1;
    const int y0   = wave * 8;

    f32x4 acc[8][2];
    #pragma unroll
    for (int dy = 0; dy < 8; ++dy) { acc[dy][0] = (f32x4)0.f; acc[dy][1] = (f32x4)0.f; }

    const char* bptr = (const char*)Bg + ((g * 16 + r) << 4);
    s16x8 bfrag = *(const s16x8*)(bptr);

    #pragma unroll 1
    for (int c = 0; c < NCHUNK; ++c) {
        int q   = 2 * c + pi;
        int ky2 = q / 9;
        int kx  = q - 9 * ky2;
        int wr  = (r - kx) & 31;
        int yb  = (y0 - 2 * ky2) & 31;
        int abase = (half << 14) + (wr << 4);

        int cn = (c < NCHUNK - 1) ? c + 1 : NCHUNK - 1;
        s16x8 bnext = *(const s16x8*)(bptr + (cn << 10));

        #pragma unroll
        for (int dy = 0; dy < 8; ++dy) {
            int yy = (yb + dy) & 31;
            int ra = abase + (yy << 9);
            s16x8 a0 = *(const s16x8*)(smb + ra);
            s16x8 a1 = *(const s16x8*)(smb + (ra ^ 256));
            acc[dy][0] = __builtin_amdgcn_mfma_f32_16x16x32_bf16(a0, bfrag, acc[dy][0], 0, 0, 0);
            acc[dy][1] = __builtin_amdgcn_mfma_f32_16x16x32_bf16(a1, bfrag, acc[dy][1], 0, 0, 0);
        }
        bfrag = bnext;
    }

    float recv[8][2][4];
    #pragma unroll
    for (int dy = 0; dy < 8; ++dy)
        #pragma unroll
        for (int h = 0; h < 2; ++h)
            #pragma unroll
            for (int i = 0; i < 4; ++i)
                recv[dy][h][i] = __shfl_xor(acc[dy][h][i], 8);

    if (r < 8) {
        #pragma unroll
        for (int h = 0; h < 2; ++h)
            *(f32x4*)&handoff[wave * 256 + r * 32 + h * 16 + g * 4] = *(f32x4*)recv[7][h];
    }
    __syncthreads();

    if (r < 8) {
        const int pw = (wave + 3) & 3;
        f32x4 prev[2];
        #pragma unroll
        for (int h = 0; h < 2; ++h)
            prev[h] = *(f32x4*)&handoff[pw * 256 + r * 32 + h * 16 + g * 4];

        float* ob = out + (((size_t)(b * 256 + r * 32 + j)) << 10) + (g << 2);
        #pragma unroll
        for (int dy = 0; dy < 8; ++dy) {
            #pragma unroll
            for (int h = 0; h < 2; ++h) {
                f32x4 t1 = (dy == 0) ? prev[h] : *(f32x4*)recv[dy - 1][h];
                f32x4 v  = acc[dy][h] + t1;
                *(f32x4*)(ob + (y0 + dy) * 32 + h * 16) = v;
            }
        }
    }
}

// ===========================================================================
// TIER 3: fp32 VALU fallback (no workspace needed).
// ===========================================================================
__global__ __launch_bounds__(256, 2) void fconv_fallback(
    const float* __restrict__ x,
    const float* __restrict__ wgt,
    float* __restrict__ out)
{
    __shared__ float sw[16 * KK * KK * 8];
    const int tid = threadIdx.x;
    for (int idx = tid; idx < 8 * 16 * KK * KK; idx += 256) {
        int n  = idx / (16 * KK * KK);
        int rm = idx - n * (16 * KK * KK);
        int dc = rm / (KK * KK);
        int r2 = rm - dc * (KK * KK);
        int ky = r2 / KK;
        int kx = r2 - ky * KK;
        sw[((dc * KK + kx) * KK + ky) * 8 + n] = wgt[idx];
    }
    __syncthreads();

    const int bid = blockIdx.x;
    const int b   = bid >> 6;
    const int j   = (bid >> 1) & 31;
    const int yh  = bid & 1;
    const int xw  = tid & 31;
    const int yg  = tid >> 5;
    const int y_base = yh * 16 + yg * 2;

    int rows[10];
    #pragma unroll
    for (int i = 0; i < 10; ++i)
        rows[i] = ((y_base + 24 + i) & 31) << 5;

    float acc[8][2];
    #pragma unroll
    for (int n = 0; n < 8; ++n) { acc[n][0] = 0.f; acc[n][1] = 0.f; }

    const int c0 = 4 * j;
    #pragma unroll 1
    for (int dc = 0; dc < 16; ++dc) {
        const int c_src = (c0 - dc) & 127;
        const float* bx = x + (((size_t)b * 128 + c_src) << 10);
        #pragma unroll 1
        for (int kx = 0; kx < KK; ++kx) {
            const int x_col = (xw - kx) & 31;
            float win[10];
            #pragma unroll
            for (int i = 0; i < 10; ++i)
                win[i] = bx[rows[i] + x_col];
            const float4* wp = (const float4*)&sw[((dc * KK + kx) * KK) * 8];
            #pragma unroll
            for (int ky = 0; ky < KK; ++ky) {
                float4 wA = wp[2 * ky];
                float4 wB = wp[2 * ky + 1];
                float x0 = win[8 - ky];
                float x1 = win[9 - ky];
                acc[0][0] += x0 * wA.x; acc[0][1] += x1 * wA.x;
                acc[1][0] += x0 * wA.y; acc[1][1] += x1 * wA.y;
                acc[2][0] += x0 * wA.z; acc[2][1] += x1 * wA.z;
                acc[3][0] += x0 * wA.w; acc[3][1] += x1 * wA.w;
                acc[4][0] += x0 * wB.x; acc[4][1] += x1 * wB.x;
                acc[5][0] += x0 * wB.y; acc[5][1] += x1 * wB.y;
                acc[6][0] += x0 * wB.z; acc[6][1] += x1 * wB.z;
                acc[7][0] += x0 * wB.w; acc[7][1] += x1 * wB.w;
            }
        }
    }
    #pragma unroll
    for (int n = 0; n < 8; ++n) {
        float* op = out + ((((size_t)b * 256) + n * 32 + j) << 10) + (y_base << 5) + xw;
        op[0]  = acc[n][0];
        op[32] = acc[n][1];
    }
}

extern "C" void kernel_launch(void* const* d_in, const int* in_sizes, int n_in,
                              void* d_out, int out_size, void* d_ws, size_t ws_size,
                              hipStream_t stream) {
    const float* x   = (const float*)d_in[0];
    const float* w   = (const float*)d_in[1];
    float*       out = (float*)d_out;

    const size_t BG32_BYTES = (size_t)108 * 64 * 8 * sizeof(unsigned short);  // 110592
    const size_t BG16_BYTES = (size_t)NCHUNK * 4 * 16 * 8 * sizeof(unsigned short);

    if (ws_size >= BG32_BYTES) {
        unsigned short* Bg = (unsigned short*)d_ws;
        prep_w32<<<216, 256, 0, stream>>>(w, Bg);
        fconv_mfma32<<<512, 512, 0, stream>>>(x, Bg, out);
    } else if (ws_size >= BG16_BYTES) {
        unsigned short* Bg = (unsigned short*)d_ws;
        prep_w<<<46, 256, 0, stream>>>(w, Bg);
        fconv_mfma<<<1024, 256, 0, stream>>>(x, Bg, out);
    } else {
        fconv_fallback<<<2048, 256, 0, stream>>>(x, w, out);
    }
}